// Round 1
// baseline (78435.132 us; speedup 1.0000x reference)
//
#include <hip/hip_runtime.h>
#include <hip/hip_bf16.h>
#include <math.h>

#define B_  64
#define T_  512
#define I_  512
#define H_  1024
#define G4_ 4096
#define O_  512

typedef short  s16x8 __attribute__((ext_vector_type(8)));
typedef float  fx4   __attribute__((ext_vector_type(4)));
typedef float  fx8   __attribute__((ext_vector_type(8)));
typedef unsigned short u16;
typedef u16    u16x4 __attribute__((ext_vector_type(4)));

__device__ __forceinline__ u16 f2bf(float f){
  unsigned u = __float_as_uint(f);
  unsigned r = u + 0x7fffu + ((u >> 16) & 1u);   // RNE
  return (u16)(r >> 16);
}
__device__ __forceinline__ float bf2f(u16 s){ return __uint_as_float(((unsigned)s) << 16); }

__device__ __forceinline__ float sigm(float x){ return 1.0f / (1.0f + __expf(-x)); }
__device__ __forceinline__ float tanh_(float x){
  float ax = fabsf(x);
  float e  = __expf(2.0f * ax);          // inf-safe: 2/(inf+1)=0 -> +/-1
  float r  = 1.0f - 2.0f / (e + 1.0f);
  return copysignf(r, x);
}

__device__ __forceinline__ fx4 mfma(s16x8 a, s16x8 b, fx4 c){
  return __builtin_amdgcn_mfma_f32_16x16x32_bf16(a, b, c, 0, 0, 0);
}

// ---------------- prep kernels ----------------
__global__ void cvt_hilo(const float* __restrict__ src, u16* __restrict__ hi,
                         u16* __restrict__ lo, int n4){
  int i      = blockIdx.x * blockDim.x + threadIdx.x;
  int stride = gridDim.x * blockDim.x;
  for (; i < n4; i += stride){
    fx4 v = ((const fx4*)src)[i];
    u16x4 h, l;
    #pragma unroll
    for (int k = 0; k < 4; ++k){
      u16 hh = f2bf(v[k]);
      h[k] = hh;
      l[k] = f2bf(v[k] - bf2f(hh));
    }
    ((u16x4*)hi)[i] = h;
    ((u16x4*)lo)[i] = l;
  }
}

__global__ void vadd(const float* __restrict__ a, const float* __restrict__ b,
                     float* __restrict__ o, int n){
  int i = blockIdx.x * blockDim.x + threadIdx.x;
  if (i < n) o[i] = a[i] + b[i];
}

// ---------------- per-timestep LSTM kernel ----------------
// grid: 64 WGs (one per 16 hidden units), 256 threads (4 waves; wave v = batch rows 16v..16v+15)
// Each WG computes gate columns {j, H+j, 2H+j, 3H+j} for its 16 hidden units, all 64 batch rows,
// so the c/h update is wave-local. Split-bf16: acc += Ahi*Bhi + Ahi*Blo + Alo*Bhi.
template<int KX, bool XF32>
__global__ __launch_bounds__(256)
void lstm_step(const float* __restrict__ xf,                       // fp32 x   (XF32)
               const u16* __restrict__ xh, const u16* __restrict__ xl,  // bf16 hi/lo x (!XF32)
               const u16* __restrict__ Wih_hi, const u16* __restrict__ Wih_lo, // [4096,KX]
               const u16* __restrict__ Whh_hi, const u16* __restrict__ Whh_lo, // [4096,1024]
               const float* __restrict__ bsum,                     // [4096] b_ih+b_hh
               const u16* __restrict__ hp_hi, const u16* __restrict__ hp_lo,   // prev h [64,1024]
               u16* __restrict__ hn_hi, u16* __restrict__ hn_lo,   // next h [64,1024]
               float* __restrict__ cst,                            // c state [64,1024] fp32
               u16* __restrict__ ha_hi, u16* __restrict__ ha_lo,   // archive [B,T,H] (lo optional)
               int t)
{
  const int lane = threadIdx.x & 63;
  const int wv   = threadIdx.x >> 6;    // 0..3
  const int l15  = lane & 15;
  const int lhi  = lane >> 4;           // 0..3
  const int koff = lhi * 8;
  const int arow = wv * 16 + l15;       // batch row for A fragment
  const int jb   = blockIdx.x * 16;     // hidden-unit base
  const int nb   = jb + l15;            // W row (col of B) for this lane

  fx4 acc[4] = {};                      // i, f, g, o

  // ---- x-projection part (K = KX) ----
  for (int kt = 0; kt < KX / 32; ++kt){
    const int kb = kt * 32 + koff;
    s16x8 a_hi, a_lo;
    if (XF32){
      const float* p = xf + ((size_t)arow * T_ + t) * KX + kb;
      fx8 v = *reinterpret_cast<const fx8*>(p);
      #pragma unroll
      for (int i = 0; i < 8; ++i){
        u16 h = f2bf(v[i]);
        a_hi[i] = (short)h;
        a_lo[i] = (short)f2bf(v[i] - bf2f(h));
      }
    } else {
      const size_t xo = ((size_t)arow * T_ + t) * KX + kb;
      a_hi = *reinterpret_cast<const s16x8*>(xh + xo);
      a_lo = *reinterpret_cast<const s16x8*>(xl + xo);
    }
    #pragma unroll
    for (int g = 0; g < 4; ++g){
      const size_t wo = ((size_t)(g * H_) + nb) * KX + kb;
      s16x8 b_hi = *reinterpret_cast<const s16x8*>(Wih_hi + wo);
      s16x8 b_lo = *reinterpret_cast<const s16x8*>(Wih_lo + wo);
      acc[g] = mfma(a_hi, b_hi, acc[g]);
      acc[g] = mfma(a_hi, b_lo, acc[g]);
      acc[g] = mfma(a_lo, b_hi, acc[g]);
    }
  }

  // ---- recurrent part (K = 1024) ----
  for (int kt = 0; kt < H_ / 32; ++kt){
    const int kb = kt * 32 + koff;
    const size_t ho = (size_t)arow * H_ + kb;
    s16x8 a_hi = *reinterpret_cast<const s16x8*>(hp_hi + ho);
    s16x8 a_lo = *reinterpret_cast<const s16x8*>(hp_lo + ho);
    #pragma unroll
    for (int g = 0; g < 4; ++g){
      const size_t wo = ((size_t)(g * H_) + nb) * H_ + kb;
      s16x8 b_hi = *reinterpret_cast<const s16x8*>(Whh_hi + wo);
      s16x8 b_lo = *reinterpret_cast<const s16x8*>(Whh_lo + wo);
      acc[g] = mfma(a_hi, b_hi, acc[g]);
      acc[g] = mfma(a_hi, b_lo, acc[g]);
      acc[g] = mfma(a_lo, b_hi, acc[g]);
    }
  }

  // ---- epilogue: gate nonlinearities + state update ----
  // D layout: col = lane&15 (hidden unit), row = (lane>>4)*4 + reg (batch)
  const int j  = jb + l15;
  const float b0 = bsum[j], b1 = bsum[H_ + j], b2 = bsum[2 * H_ + j], b3 = bsum[3 * H_ + j];
  #pragma unroll
  for (int r = 0; r < 4; ++r){
    const int m  = wv * 16 + lhi * 4 + r;
    const int ci = m * H_ + j;
    float iv = sigm (acc[0][r] + b0);
    float fv = sigm (acc[1][r] + b1);
    float gv = tanh_(acc[2][r] + b2);
    float ov = sigm (acc[3][r] + b3);
    float cn = fv * cst[ci] + iv * gv;
    float hn = ov * tanh_(cn);
    cst[ci] = cn;
    u16 hh = f2bf(hn);
    u16 hl = f2bf(hn - bf2f(hh));
    hn_hi[ci] = hh;
    hn_lo[ci] = hl;
    const size_t ai = ((size_t)m * T_ + t) * H_ + j;
    ha_hi[ai] = hh;
    if (ha_lo) ha_lo[ai] = hl;
  }
}

// ---------------- final FC: out[m,n] = sum_k h2[m,k]*fcW[n,k] + fcb[n] ----------------
__global__ __launch_bounds__(256)
void fc_kernel(const u16* __restrict__ h2,                        // [32768,1024] bf16 hi
               const u16* __restrict__ W_hi, const u16* __restrict__ W_lo, // [512,1024]
               const float* __restrict__ bias,                    // [512]
               float* __restrict__ out)                           // [32768,512]
{
  const int lane = threadIdx.x & 63;
  const int wv   = threadIdx.x >> 6;
  const int l15  = lane & 15;
  const int lhi  = lane >> 4;
  const int koff = lhi * 8;
  const int mb   = blockIdx.x * 64 + wv * 16;   // 512 row tiles of 64
  const int nb   = blockIdx.y * 64;             // 8 col tiles of 64
  const int arow = mb + l15;

  fx4 acc[4] = {};
  for (int kt = 0; kt < H_ / 32; ++kt){
    const int kb = kt * 32 + koff;
    s16x8 a = *reinterpret_cast<const s16x8*>(h2 + (size_t)arow * H_ + kb);
    #pragma unroll
    for (int c = 0; c < 4; ++c){
      const size_t wo = (size_t)(nb + c * 16 + l15) * H_ + kb;
      s16x8 bh = *reinterpret_cast<const s16x8*>(W_hi + wo);
      s16x8 bl = *reinterpret_cast<const s16x8*>(W_lo + wo);
      acc[c] = mfma(a, bh, acc[c]);
      acc[c] = mfma(a, bl, acc[c]);
    }
  }
  #pragma unroll
  for (int c = 0; c < 4; ++c){
    const int n = nb + c * 16 + l15;
    const float bv = bias[n];
    #pragma unroll
    for (int r = 0; r < 4; ++r){
      const int m = mb + lhi * 4 + r;
      out[(size_t)m * O_ + n] = acc[c][r] + bv;
    }
  }
}

// ---------------- host launch ----------------
extern "C" void kernel_launch(void* const* d_in, const int* in_sizes, int n_in,
                              void* d_out, int out_size, void* d_ws, size_t ws_size,
                              hipStream_t stream)
{
  const float* x    = (const float*)d_in[0];
  const float* Wih1 = (const float*)d_in[1];
  const float* Whh1 = (const float*)d_in[2];
  const float* bih1 = (const float*)d_in[3];
  const float* bhh1 = (const float*)d_in[4];
  const float* Wih2 = (const float*)d_in[5];
  const float* Whh2 = (const float*)d_in[6];
  const float* bih2 = (const float*)d_in[7];
  const float* bhh2 = (const float*)d_in[8];
  const float* fcW  = (const float*)d_in[9];
  const float* fcb  = (const float*)d_in[10];
  float* out = (float*)d_out;
  (void)in_sizes; (void)n_in; (void)out_size; (void)ws_size;

  char* base = (char*)d_ws;
  size_t off = 0;
  auto alloc = [&](size_t bytes) -> void* {
    void* p = base + off;
    off = (off + bytes + 255) & ~(size_t)255;
    return p;
  };
  u16* Wih1_hi = (u16*)alloc((size_t)G4_ * I_ * 2);
  u16* Wih1_lo = (u16*)alloc((size_t)G4_ * I_ * 2);
  u16* Whh1_hi = (u16*)alloc((size_t)G4_ * H_ * 2);
  u16* Whh1_lo = (u16*)alloc((size_t)G4_ * H_ * 2);
  u16* Wih2_hi = (u16*)alloc((size_t)G4_ * H_ * 2);
  u16* Wih2_lo = (u16*)alloc((size_t)G4_ * H_ * 2);
  u16* Whh2_hi = (u16*)alloc((size_t)G4_ * H_ * 2);
  u16* Whh2_lo = (u16*)alloc((size_t)G4_ * H_ * 2);
  u16* fcW_hi  = (u16*)alloc((size_t)O_ * H_ * 2);
  u16* fcW_lo  = (u16*)alloc((size_t)O_ * H_ * 2);
  float* bsum1 = (float*)alloc((size_t)G4_ * 4);
  float* bsum2 = (float*)alloc((size_t)G4_ * 4);
  float* cst   = (float*)alloc((size_t)B_ * H_ * 4);
  u16* hb_hi0  = (u16*)alloc((size_t)B_ * H_ * 2);
  u16* hb_hi1  = (u16*)alloc((size_t)B_ * H_ * 2);
  u16* hb_lo0  = (u16*)alloc((size_t)B_ * H_ * 2);
  u16* hb_lo1  = (u16*)alloc((size_t)B_ * H_ * 2);
  u16* h1s_hi  = (u16*)alloc((size_t)B_ * T_ * H_ * 2);
  u16* h1s_lo  = (u16*)alloc((size_t)B_ * T_ * H_ * 2);
  u16* h2s_hi  = (u16*)alloc((size_t)B_ * T_ * H_ * 2);

  u16* hb_hi[2] = { hb_hi0, hb_hi1 };
  u16* hb_lo[2] = { hb_lo0, hb_lo1 };

  // prep: weight hi/lo split + combined biases
  cvt_hilo<<<512, 256, 0, stream>>>(Wih1, Wih1_hi, Wih1_lo, G4_ * I_ / 4);
  cvt_hilo<<<512, 256, 0, stream>>>(Whh1, Whh1_hi, Whh1_lo, G4_ * H_ / 4);
  cvt_hilo<<<512, 256, 0, stream>>>(Wih2, Wih2_hi, Wih2_lo, G4_ * H_ / 4);
  cvt_hilo<<<512, 256, 0, stream>>>(Whh2, Whh2_hi, Whh2_lo, G4_ * H_ / 4);
  cvt_hilo<<<256, 256, 0, stream>>>(fcW,  fcW_hi,  fcW_lo,  O_ * H_ / 4);
  vadd<<<16, 256, 0, stream>>>(bih1, bhh1, bsum1, G4_);
  vadd<<<16, 256, 0, stream>>>(bih2, bhh2, bsum2, G4_);

  // layer 1
  hipMemsetAsync(cst, 0, (size_t)B_ * H_ * 4, stream);
  hipMemsetAsync(hb_hi[0], 0, (size_t)B_ * H_ * 2, stream);
  hipMemsetAsync(hb_lo[0], 0, (size_t)B_ * H_ * 2, stream);
  for (int t = 0; t < T_; ++t){
    lstm_step<I_, true><<<64, 256, 0, stream>>>(
        x, nullptr, nullptr,
        Wih1_hi, Wih1_lo, Whh1_hi, Whh1_lo, bsum1,
        hb_hi[t & 1], hb_lo[t & 1], hb_hi[(t + 1) & 1], hb_lo[(t + 1) & 1],
        cst, h1s_hi, h1s_lo, t);
  }

  // layer 2
  hipMemsetAsync(cst, 0, (size_t)B_ * H_ * 4, stream);
  hipMemsetAsync(hb_hi[0], 0, (size_t)B_ * H_ * 2, stream);
  hipMemsetAsync(hb_lo[0], 0, (size_t)B_ * H_ * 2, stream);
  for (int t = 0; t < T_; ++t){
    lstm_step<H_, false><<<64, 256, 0, stream>>>(
        nullptr, h1s_hi, h1s_lo,
        Wih2_hi, Wih2_lo, Whh2_hi, Whh2_lo, bsum2,
        hb_hi[t & 1], hb_lo[t & 1], hb_hi[(t + 1) & 1], hb_lo[(t + 1) & 1],
        cst, h2s_hi, nullptr, t);
  }

  // final FC
  fc_kernel<<<dim3(512, 8), 256, 0, stream>>>(h2s_hi, fcW_hi, fcW_lo, fcb, out);
}